// Round 3
// baseline (279.787 us; speedup 1.0000x reference)
//
#include <hip/hip_runtime.h>
#include <hip/hip_bf16.h>

// Hopfield sparsemax attention, MI355X gfx950.
// B=1, L=S=2048, D_MODEL=1024, H=16, DK=64. Inputs fp32 (runtime-detected), output per flag.
//
// Round-12 (attn: strip the append/fold machinery):
//   - Lane-private candidate segments: 64 writer-lanes per row x 3 slots (192) +
//     64-slot shared overflow (atomicAdd only on a lane's 4th keep). No ballots,
//     no popc, no per-quad LDS atomics, no shfl broadcast in the append path.
//   - Unused slots sentinel-filled (bf16 -inf). Michelot tau0 = g1-1 (valid lower
//     bound: support subset of {v > g1-1} since tau* >= g1-1), monotone-increasing
//     iteration => sentinels never enter the active set, ~2 fewer iterations.
//   - Score scale 1/8 folded into Q projection epilogue (exact pow2; commutes with
//     bf16 rounding) via per-job oscale.
//   - Keeps R11 structure: 16 rows/block, 4 waves x column quarters, direct-global K
//     (L2-resident), barrier-free main loop, head->XCD pinning, top-2 threshold
//     thr = max(g1-1, (g1+m2-1)/2) <= tau.
//   Rest of pipeline unchanged (convert, transpose4, 64x64 gemm, final projection).

typedef __attribute__((ext_vector_type(8))) short short8;
typedef __attribute__((ext_vector_type(4))) float floatx4;

#define SRC_BF16 0
#define SRC_F32  1
#define SRC_RT   2
#define NSEG 3            // private slots per writer lane
#define OVF 64            // shared overflow slots per row
#define CAPT (64 * NSEG + OVF)   // 256 u32 per row

__device__ __forceinline__ short f2bf(float f) {
    __hip_bfloat16 h = __float2bfloat16(f);
    return *reinterpret_cast<const short*>(&h);
}
__device__ __forceinline__ unsigned short f2bfu(float f) {
    __hip_bfloat16 h = __float2bfloat16(f);
    return *reinterpret_cast<const unsigned short*>(&h);
}
__device__ __forceinline__ float bf2f(unsigned short u) {
    return __uint_as_float(((unsigned)u) << 16);
}
// monotone float->uint map (order-preserving for all finite floats)
__device__ __forceinline__ unsigned fmap(float f) {
    unsigned u = __float_as_uint(f);
    return (u & 0x80000000u) ? ~u : (u | 0x80000000u);
}
__device__ __forceinline__ float funmap(unsigned u) {
    return (u & 0x80000000u) ? __uint_as_float(u ^ 0x80000000u) : __uint_as_float(~u);
}

// Detect input dtype: decode first n shorts as bf16; fp32-read-as-bf16 almost surely
// yields |x|>1e10 / inf / NaN. One 64-thread block.
__global__ void detect_k(const short* __restrict__ q, int n, int* __restrict__ flag)
{
    const int tid = threadIdx.x;
    int bad = 0;
    for (int i = tid; i < n; i += 64) {
        float f = bf2f((unsigned short)q[i]);
        if (!(fabsf(f) < 1e10f)) bad = 1;
    }
    unsigned long long m = __ballot(bad != 0);
    if (tid == 0) *flag = (m != 0ULL) ? 1 : 0;
}

// Flat convert (fp32|bf16 per flag) -> bf16. z selects one of two sources.
__global__ __launch_bounds__(256)
void convert2_k(const void* __restrict__ s0, const void* __restrict__ s1,
                short* __restrict__ d0, short* __restrict__ d1,
                const int* __restrict__ dflag)
{
    const void* s = blockIdx.z ? s1 : s0;
    short* d = blockIdx.z ? d1 : d0;
    const size_t i = ((size_t)blockIdx.x * 256 + threadIdx.x) * 8;
    short8 o;
    if (*dflag) {
        const float4 f0 = ((const float4*)((const float*)s + i))[0];
        const float4 f1 = ((const float4*)((const float*)s + i))[1];
        o[0] = f2bf(f0.x); o[1] = f2bf(f0.y); o[2] = f2bf(f0.z); o[3] = f2bf(f0.w);
        o[4] = f2bf(f1.x); o[5] = f2bf(f1.y); o[6] = f2bf(f1.z); o[7] = f2bf(f1.w);
    } else {
        o = *(const short8*)((const short*)s + i);
    }
    *(short8*)(d + i) = o;
}

// Batched weight transpose: 4 matrices [R,C] -> bf16 [C,R], selected by blockIdx.z.
struct TP4 {
    const void* s[4];
    short* d[4];
};
__global__ __launch_bounds__(256)
void transpose4_k(TP4 p, int R, int C, const int* __restrict__ dflag)
{
    __shared__ short T[64][72];
    const int tid = threadIdx.x;
    const int bC = blockIdx.x, bR = blockIdx.y;
    const void* src = p.s[blockIdx.z];
    short* dst = p.d[blockIdx.z];
    const bool f32 = (*dflag != 0);

    const int colg = (tid & 7) * 8;
    #pragma unroll
    for (int h = 0; h < 2; ++h) {
        const int row = (tid >> 3) + 32 * h;
        const size_t idx = (size_t)(bR * 64 + row) * (size_t)C + (size_t)(bC * 64 + colg);
        short e[8];
        if (f32) {
            const float4 f0 = ((const float4*)((const float*)src + idx))[0];
            const float4 f1 = ((const float4*)((const float*)src + idx))[1];
            e[0] = f2bf(f0.x); e[1] = f2bf(f0.y); e[2] = f2bf(f0.z); e[3] = f2bf(f0.w);
            e[4] = f2bf(f1.x); e[5] = f2bf(f1.y); e[6] = f2bf(f1.z); e[7] = f2bf(f1.w);
        } else {
            short8 s = *(const short8*)((const short*)src + idx);
            #pragma unroll
            for (int j = 0; j < 8; ++j) e[j] = s[j];
        }
        #pragma unroll
        for (int j = 0; j < 8; ++j) T[colg + j][row] = e[j];
    }
    __syncthreads();
    #pragma unroll
    for (int h = 0; h < 2; ++h) {
        const int orow = (tid >> 3) + 32 * h;
        const int ocolg = (tid & 7) * 8;
        const size_t idx = (size_t)(bC * 64 + orow) * (size_t)R + (size_t)(bR * 64 + ocolg);
        *(short8*)(dst + idx) = *(const short8*)&T[orow][ocolg];
    }
}

// ---------------- 64x64-tile GEMM, bf16 A [2048,1024] x bf16 Bt [1024,1024] ----------
// C = (A@Bt^T + bias) * os. Two independent jobs selectable via blockIdx.z.
struct GJ { const short* A; const short* B; const void* bias; void* C; float os; };

template<int OSRC>
__global__ __launch_bounds__(256)
void gemm64_bt_k(GJ j0, GJ j1, const int* __restrict__ dflag)
{
    __shared__ __align__(16) short As[64][40];
    __shared__ __align__(16) short Bs[64][40];

    const GJ j = blockIdx.z ? j1 : j0;
    const int rtf = *dflag;

    const int tid  = threadIdx.x;
    const int bN   = blockIdx.x, bM = blockIdx.y;
    const int lane = tid & 63, wave = tid >> 6;
    const int wm   = (wave >> 1) * 32;
    const int wn   = (wave & 1) * 32;
    const int quad = lane >> 4, r16 = lane & 15;

    floatx4 acc[2][2];
    #pragma unroll
    for (int i = 0; i < 2; ++i)
        #pragma unroll
        for (int jj = 0; jj < 2; ++jj)
            acc[i][jj] = (floatx4){0.f, 0.f, 0.f, 0.f};

    const int ar = tid >> 2, ac = (tid & 3) * 8;

    for (int k0 = 0; k0 < 1024; k0 += 32) {
        *(short8*)&As[ar][ac] =
            *(const short8*)(j.A + (size_t)(bM * 64 + ar) * 1024 + (size_t)(k0 + ac));
        *(short8*)&Bs[ar][ac] =
            *(const short8*)(j.B + (size_t)(bN * 64 + ar) * 1024 + (size_t)(k0 + ac));
        __syncthreads();

        short8 a0 = *(const short8*)&As[wm + r16][quad * 8];
        short8 a1 = *(const short8*)&As[wm + 16 + r16][quad * 8];
        short8 b0 = *(const short8*)&Bs[wn + r16][quad * 8];
        short8 b1 = *(const short8*)&Bs[wn + 16 + r16][quad * 8];

        acc[0][0] = __builtin_amdgcn_mfma_f32_16x16x32_bf16(a0, b0, acc[0][0], 0, 0, 0);
        acc[0][1] = __builtin_amdgcn_mfma_f32_16x16x32_bf16(a0, b1, acc[0][1], 0, 0, 0);
        acc[1][0] = __builtin_amdgcn_mfma_f32_16x16x32_bf16(a1, b0, acc[1][0], 0, 0, 0);
        acc[1][1] = __builtin_amdgcn_mfma_f32_16x16x32_bf16(a1, b1, acc[1][1], 0, 0, 0);
        __syncthreads();
    }

    const bool of32 = (OSRC == SRC_F32) || (OSRC == SRC_RT && rtf);
    #pragma unroll
    for (int jj = 0; jj < 2; ++jj) {
        const int gc = bN * 64 + wn + jj * 16 + r16;
        const float bb = rtf ? ((const float*)j.bias)[gc]
                             : bf2f(((const unsigned short*)j.bias)[gc]);
        #pragma unroll
        for (int i = 0; i < 2; ++i) {
            #pragma unroll
            for (int rg = 0; rg < 4; ++rg) {
                const int gr = bM * 64 + wm + i * 16 + quad * 4 + rg;
                const float v = (acc[i][jj][rg] + bb) * j.os;
                if (of32)
                    ((float*)j.C)[(size_t)gr * 1024 + gc] = v;
                else
                    ((__hip_bfloat16*)j.C)[(size_t)gr * 1024 + gc] = __float2bfloat16(v);
            }
        }
    }
}

// ---------------- fused attention v6: lane-private candidate segments ----------------
// Block = 16 Q-rows x 1 head, 256 threads (4 waves), LDS ~16.5 KB -> 8 blocks/CU.
// Wave w owns ALL 16 rows x column quarter w. K fragments direct from global (L2-hot).
// Barrier-free main loop. Per 256-col step: 8 MFMA -> top-2 fold -> atomicMax rmax ->
// per-lane keep test (val >= thr) appending into the lane's PRIVATE 3-slot segment of
// cpk[row] (overflow -> shared 64-slot region via atomicAdd, rare). Q pre-scaled by
// 1/8 in the projection. Tail: sentinel-aware Michelot from tau0 = g1-1, ballot-compact,
// 4-deep sparse PV gather.
__global__ __launch_bounds__(256, 8)
void attn_fused_k(const short* __restrict__ Qb, const short* __restrict__ Kb,
                  const short* __restrict__ Vb, short* __restrict__ Ob)
{
    __shared__ unsigned cpk[16][CAPT];
    __shared__ unsigned rmax[16];
    __shared__ int cnt[16];

    const int tid  = threadIdx.x;
    const int lane = tid & 63, wave = tid >> 6;
    const int quad = lane >> 4, r16 = lane & 15;

    // head->XCD pinning: blocks with bid%8==x carry heads x and x+8.
    const int bid  = blockIdx.x;
    const int slot = bid >> 3;
    const int h    = (slot & 1) * 8 + (bid & 7);
    const int row0 = (slot >> 1) * 16;

    if (tid < 16) { rmax[tid] = fmap(-3.0e38f); cnt[tid] = 0; }
    __syncthreads();

    // Q fragment, direct from global (all 4 waves read the same 2 KB; L1-hot)
    const short* qp = Qb + (size_t)(row0 + r16) * 1024 + h * 64 + quad * 8;
    const short8 qa0 = *(const short8*)qp;
    const short8 qa1 = *(const short8*)(qp + 32);

    const int myrow = quad * 4;                // + rg
    const int wid   = wave * 16 + r16;         // writer id 0..63 (per row)
    const short* kp0 = Kb + (size_t)(wave * 16 + r16) * 1024 + h * 64 + quad * 8;

    // wave-local running top-2 per owned row (over this wave's column quarter)
    float rm1[4], rm2[4];
    int mycnt[4];
    #pragma unroll
    for (int rg = 0; rg < 4; ++rg) { rm1[rg] = -3.0e38f; rm2[rg] = -3.0e38f; mycnt[rg] = 0; }

    for (int s0 = 0; s0 < 2048; s0 += 256) {
        floatx4 acc[4];
        #pragma unroll
        for (int t = 0; t < 4; ++t) {
            const short* kp = kp0 + (size_t)(s0 + t * 64) * 1024;
            const short8 b0 = *(const short8*)kp;
            const short8 b1 = *(const short8*)(kp + 32);
            floatx4 a = (floatx4){0.f, 0.f, 0.f, 0.f};
            a = __builtin_amdgcn_mfma_f32_16x16x32_bf16(qa0, b0, a, 0, 0, 0);
            a = __builtin_amdgcn_mfma_f32_16x16x32_bf16(qa1, b1, a, 0, 0, 0);
            acc[t] = a;   // scale 1/8 pre-folded into Qb
        }

        // per-row tile top-2 fold (lane-local 4 vals, 16-lane butterfly), merge into
        // running top-2, post m1 to shared rmax (barrier-free; monotone)
        #pragma unroll
        for (int rg = 0; rg < 4; ++rg) {
            float m1ab = fmaxf(acc[0][rg], acc[1][rg]);
            float m2ab = fminf(acc[0][rg], acc[1][rg]);
            float m1cd = fmaxf(acc[2][rg], acc[3][rg]);
            float m2cd = fminf(acc[2][rg], acc[3][rg]);
            float m1 = fmaxf(m1ab, m1cd);
            float m2 = fmaxf(fminf(m1ab, m1cd), (m1ab >= m1cd) ? m2ab : m2cd);
            #pragma unroll
            for (int off = 1; off < 16; off <<= 1) {
                const float o1 = __shfl_xor(m1, off, 64);
                const float o2 = __shfl_xor(m2, off, 64);
                const float n2 = fmaxf(fminf(m1, o1), (m1 >= o1) ? m2 : o2);
                m1 = fmaxf(m1, o1);
                m2 = n2;
            }
            const float n1 = fmaxf(rm1[rg], m1);
            rm2[rg] = fmaxf(fminf(rm1[rg], m1), (rm1[rg] >= m1) ? rm2[rg] : m2);
            rm1[rg] = n1;
            if (r16 == 0) atomicMax(&rmax[myrow + rg], fmap(m1));
        }

        // lane-private append of candidates z >= thr (no ballots, no atomics except
        // rare overflow; any rmax read is a valid lower bound, own rm1 folded in)
        #pragma unroll
        for (int rg = 0; rg < 4; ++rg) {
            const int row = myrow + rg;
            const float g1 = fmaxf(funmap(rmax[row]), rm1[rg]);
            const float thr = fmaxf(g1 - 1.0f, 0.5f * (g1 + rm2[rg]) - 0.5f);
            #pragma unroll
            for (int t = 0; t < 4; ++t) {
                const float val = acc[t][rg];
                if (val >= thr) {
                    const unsigned pk = ((unsigned)f2bfu(val) << 16)
                                      | (unsigned)(s0 + wave * 16 + t * 64 + r16);
                    const int c = mycnt[rg];
                    if (c < NSEG) {
                        cpk[row][wid * NSEG + c] = pk;
                    } else {
                        const int p = atomicAdd(&cnt[row], 1);
                        if (p < OVF) cpk[row][64 * NSEG + p] = pk;
                    }
                    mycnt[rg] = c + 1;
                }
            }
        }
    }

    // sentinel-fill unused private slots (bf16 -inf packed)
    #pragma unroll
    for (int rg = 0; rg < 4; ++rg) {
        const int row = myrow + rg;
        for (int k = mycnt[rg]; k < NSEG; ++k)
            cpk[row][wid * NSEG + k] = 0xFF800000u;
    }
    __syncthreads();   // all appends visible

    // ---- per-wave Michelot + PV on owned rows (wave w: rows w*4 .. w*4+3) ----
    const unsigned long long pre = (1ULL << lane) - 1ULL;
    for (int rr = 0; rr < 4; ++rr) {
        const int r = wave * 4 + rr;
        const int novf = min(cnt[r], OVF);

        float v[4];
        unsigned short ii[4];
        #pragma unroll
        for (int i = 0; i < 3; ++i) {
            const unsigned u = cpk[r][lane + i * 64];
            v[i] = bf2f((unsigned short)(u >> 16));
            ii[i] = (unsigned short)(u & 0xFFFFu);
        }
        if (lane < novf) {
            const unsigned u = cpk[r][64 * NSEG + lane];
            v[3] = bf2f((unsigned short)(u >> 16));
            ii[3] = (unsigned short)(u & 0xFFFFu);
        } else { v[3] = -3.0e38f; ii[3] = 0; }

        // Michelot from valid lower bound tau0 = g1-1 (monotone increasing)
        float tau = funmap(rmax[r]) - 1.0f, prevc = -1.0f;
        for (int it = 0; it < 24; ++it) {
            float s = 0.f, c = 0.f;
            #pragma unroll
            for (int i = 0; i < 4; ++i)
                if (v[i] > tau) { s += v[i]; c += 1.f; }
            #pragma unroll
            for (int off = 1; off < 64; off <<= 1) {
                s += __shfl_xor(s, off, 64);
                c += __shfl_xor(c, off, 64);
            }
            if (c == prevc) break;
            prevc = c;
            tau = (s - 1.0f) / c;
        }

        // ballot-compact support (p>0) to list front, p packed bf16
        int base = 0;
        #pragma unroll
        for (int i = 0; i < 4; ++i) {
            const float p = v[i] - tau;
            const unsigned long long m = __ballot(p > 0.f);
            const int w = base + __popcll(m & pre);
            if (p > 0.f) cpk[r][w] = ((unsigned)f2bfu(p) << 16) | (unsigned)ii[i];
            base += __popcll(m);
        }
        const int msup = base;

        // sparse PV gather: lane = output col; 4-deep independent loads
        const unsigned short* vb = (const unsigned short*)Vb + (size_t)h * 64 + lane;
        float o0 = 0.f, o1 = 0.f, o2 = 0.f, o3 = 0.f;
        int jj = 0;
        for (; jj + 4 <= msup; jj += 4) {
            const unsigned u0 = cpk[r][jj],     u1 = cpk[r][jj + 1];
            const unsigned u2 = cpk[r][jj + 2], u3 = cpk[r][jj + 3];
            o0 += bf2f((unsigned short)(u0 >> 16)) * bf2f(vb[(size_t)(u0 & 0xFFFFu) * 1024]);
            o1 += bf2f((unsigned short)(u1 >> 16)) * bf2f(vb[(size_t)(u1 & 0xFFFFu) * 1024]);
            o2 += bf2f((unsigned short)(u2 >> 16)) * bf2f(vb[(size_t)(u2 & 0xFFFFu) * 1024]);
            o3 += bf2f((unsigned short)(u3 >> 16)) * bf2f(vb[(size_t)(u3 & 0xFFFFu) * 1024]);
        }
        for (; jj < msup; ++jj) {
            const unsigned u0 = cpk[r][jj];
            o0 += bf2f((unsigned short)(u0 >> 16)) * bf2f(vb[(size_t)(u0 & 0xFFFFu) * 1024]);
        }
        Ob[((size_t)h * 2048 + row0 + r) * 64 + lane] = f2bf(o0 + o1 + o2 + o3);
    }
}

extern "C" void kernel_launch(void* const* d_in, const int* in_sizes, int n_in,
                              void* d_out, int out_size, void* d_ws, size_t ws_size,
                              hipStream_t stream)
{
    (void)in_sizes; (void)n_in; (void)out_size; (void)ws_size;

    const void* queries = d_in[0];
    const void* keys    = d_in[1];
    // d_in[2] ("values") unused by the reference.
    const void* Wq = d_in[3];
    const void* bq = d_in[4];
    const void* Wk = d_in[5];
    const void* bk = d_in[6];
    const void* Wv = d_in[7];
    const void* bv = d_in[8];
    const void* Wo = d_in[9];
    const void* bo = d_in[10];

    const int L = 2048, DM = 1024;
    const size_t LD = (size_t)L * DM;   // 2M elements

    int*   flag = (int*)d_ws;
    short* Qc  = (short*)((char*)d_ws + 256);  // bf16 queries      [2048,1024]
    short* Kc  = Qc + LD;                      // bf16 keys         [2048,1024]
    short* WqT = Kc + LD;                      // bf16 Wq^T         [1024,1024]
    short* WkT = WqT + (size_t)DM * DM;
    short* WvT = WkT + (size_t)DM * DM;
    short* WoT = WvT + (size_t)DM * DM;
    short* Qb  = WoT + (size_t)DM * DM;        // [2048,1024] (pre-scaled by 1/8)
    short* Kb  = Qb + LD;
    short* Vb  = Kb + LD;
    short* Ob  = Vb + LD;                      // [H,2048,64] contiguous (== mixed view)

    dim3 blk(256);

    // 0) dtype detection
    detect_k<<<dim3(1), dim3(64), 0, stream>>>((const short*)queries, 4096, flag);

    // p1) convert queries/keys -> bf16
    convert2_k<<<dim3((unsigned)(LD / 2048), 1, 2), blk, 0, stream>>>(
        queries, keys, Qc, Kc, flag);

    // p2) transpose-convert the 4 weight matrices -> bf16 [N][K]
    {
        TP4 p;
        p.s[0] = Wq; p.s[1] = Wk; p.s[2] = Wv; p.s[3] = Wo;
        p.d[0] = WqT; p.d[1] = WkT; p.d[2] = WvT; p.d[3] = WoT;
        transpose4_k<<<dim3(DM / 64, DM / 64, 4), blk, 0, stream>>>(p, DM, DM, flag);
    }

    // 1) Qb & Kb projections batched (Q job pre-scales by 1/8; exact pow2)
    {
        GJ jq{(const short*)Qc, WqT, bq, Qb, 0.125f};
        GJ jk{(const short*)Kc, WkT, bk, Kb, 1.0f};
        gemm64_bt_k<SRC_BF16><<<dim3(DM / 64, L / 64, 2), blk, 0, stream>>>(jq, jk, flag);
    }
    // 2) Vb = Kb @ WvT + bv   (reference quirk: V from key projection)
    {
        GJ jv{(const short*)Kb, WvT, bv, Vb, 1.0f};
        gemm64_bt_k<SRC_BF16><<<dim3(DM / 64, L / 64, 1), blk, 0, stream>>>(jv, jv, flag);
    }

    // 3) fused attention (scores never reach HBM; barrier-free main loop)
    attn_fused_k<<<dim3((L / 16) * 16), blk, 0, stream>>>(Qb, Kb, Vb, Ob);

    // 4) out = Ob(viewed [2048,1024]) @ WoT + bo -> d_out (dtype per flag)
    {
        GJ jo{(const short*)Ob, WoT, bo, d_out, 1.0f};
        gemm64_bt_k<SRC_RT><<<dim3(DM / 64, L / 64, 1), blk, 0, stream>>>(jo, jo, flag);
    }
}

// Round 4
// 269.048 us; speedup vs baseline: 1.0399x; 1.0399x over previous
//
#include <hip/hip_runtime.h>
#include <hip/hip_bf16.h>

// Hopfield sparsemax attention, MI355X gfx950.
// B=1, L=S=2048, D_MODEL=1024, H=16, DK=64. Inputs fp32 (runtime-detected), output per flag.
//
// Round-13 (GEMM rebuild, T3-minimum 2-phase pipeline):
//   - gemm64_bt_k: BK 32->64 (8 MFMA per barrier, half the barriers), double-buffered
//     LDS (32 KB), staging via global_load_lds width=16 (linear LDS dest), with
//     XOR-swizzled global SOURCE + XOR-swizzled ds_read (phys colgrp = logical ^ (row&7),
//     involution) for near-conflict-free fragment reads. Next K-tile issued BEFORE the
//     MFMA phase; single __syncthreads per stage drains it (loads fly under compute).
//     K-accumulation order unchanged -> bit-identical results.
//   - attn: PV sparse gather 4->8-deep ILP. Rest unchanged from R12.
//   Pipeline: detect -> convert -> transpose4 -> QK-proj(z2) -> V-proj -> attn -> O-proj.

typedef __attribute__((ext_vector_type(8))) short short8;
typedef __attribute__((ext_vector_type(4))) float floatx4;

#define SRC_BF16 0
#define SRC_F32  1
#define SRC_RT   2
#define NSEG 3            // private slots per writer lane
#define OVF 64            // shared overflow slots per row
#define CAPT (64 * NSEG + OVF)   // 256 u32 per row

typedef __attribute__((address_space(1))) const void GAS;
typedef __attribute__((address_space(3))) void LAS;
#define GLOAD16(g, l) __builtin_amdgcn_global_load_lds((GAS*)(g), (LAS*)(l), 16, 0, 0)

__device__ __forceinline__ short f2bf(float f) {
    __hip_bfloat16 h = __float2bfloat16(f);
    return *reinterpret_cast<const short*>(&h);
}
__device__ __forceinline__ unsigned short f2bfu(float f) {
    __hip_bfloat16 h = __float2bfloat16(f);
    return *reinterpret_cast<const unsigned short*>(&h);
}
__device__ __forceinline__ float bf2f(unsigned short u) {
    return __uint_as_float(((unsigned)u) << 16);
}
// monotone float->uint map (order-preserving for all finite floats)
__device__ __forceinline__ unsigned fmap(float f) {
    unsigned u = __float_as_uint(f);
    return (u & 0x80000000u) ? ~u : (u | 0x80000000u);
}
__device__ __forceinline__ float funmap(unsigned u) {
    return (u & 0x80000000u) ? __uint_as_float(u ^ 0x80000000u) : __uint_as_float(~u);
}

// Detect input dtype: decode first n shorts as bf16; fp32-read-as-bf16 almost surely
// yields |x|>1e10 / inf / NaN. One 64-thread block.
__global__ void detect_k(const short* __restrict__ q, int n, int* __restrict__ flag)
{
    const int tid = threadIdx.x;
    int bad = 0;
    for (int i = tid; i < n; i += 64) {
        float f = bf2f((unsigned short)q[i]);
        if (!(fabsf(f) < 1e10f)) bad = 1;
    }
    unsigned long long m = __ballot(bad != 0);
    if (tid == 0) *flag = (m != 0ULL) ? 1 : 0;
}

// Flat convert (fp32|bf16 per flag) -> bf16. z selects one of two sources.
__global__ __launch_bounds__(256)
void convert2_k(const void* __restrict__ s0, const void* __restrict__ s1,
                short* __restrict__ d0, short* __restrict__ d1,
                const int* __restrict__ dflag)
{
    const void* s = blockIdx.z ? s1 : s0;
    short* d = blockIdx.z ? d1 : d0;
    const size_t i = ((size_t)blockIdx.x * 256 + threadIdx.x) * 8;
    short8 o;
    if (*dflag) {
        const float4 f0 = ((const float4*)((const float*)s + i))[0];
        const float4 f1 = ((const float4*)((const float*)s + i))[1];
        o[0] = f2bf(f0.x); o[1] = f2bf(f0.y); o[2] = f2bf(f0.z); o[3] = f2bf(f0.w);
        o[4] = f2bf(f1.x); o[5] = f2bf(f1.y); o[6] = f2bf(f1.z); o[7] = f2bf(f1.w);
    } else {
        o = *(const short8*)((const short*)s + i);
    }
    *(short8*)(d + i) = o;
}

// Batched weight transpose: 4 matrices [R,C] -> bf16 [C,R], selected by blockIdx.z.
struct TP4 {
    const void* s[4];
    short* d[4];
};
__global__ __launch_bounds__(256)
void transpose4_k(TP4 p, int R, int C, const int* __restrict__ dflag)
{
    __shared__ short T[64][72];
    const int tid = threadIdx.x;
    const int bC = blockIdx.x, bR = blockIdx.y;
    const void* src = p.s[blockIdx.z];
    short* dst = p.d[blockIdx.z];
    const bool f32 = (*dflag != 0);

    const int colg = (tid & 7) * 8;
    #pragma unroll
    for (int h = 0; h < 2; ++h) {
        const int row = (tid >> 3) + 32 * h;
        const size_t idx = (size_t)(bR * 64 + row) * (size_t)C + (size_t)(bC * 64 + colg);
        short e[8];
        if (f32) {
            const float4 f0 = ((const float4*)((const float*)src + idx))[0];
            const float4 f1 = ((const float4*)((const float*)src + idx))[1];
            e[0] = f2bf(f0.x); e[1] = f2bf(f0.y); e[2] = f2bf(f0.z); e[3] = f2bf(f0.w);
            e[4] = f2bf(f1.x); e[5] = f2bf(f1.y); e[6] = f2bf(f1.z); e[7] = f2bf(f1.w);
        } else {
            short8 s = *(const short8*)((const short*)src + idx);
            #pragma unroll
            for (int j = 0; j < 8; ++j) e[j] = s[j];
        }
        #pragma unroll
        for (int j = 0; j < 8; ++j) T[colg + j][row] = e[j];
    }
    __syncthreads();
    #pragma unroll
    for (int h = 0; h < 2; ++h) {
        const int orow = (tid >> 3) + 32 * h;
        const int ocolg = (tid & 7) * 8;
        const size_t idx = (size_t)(bC * 64 + orow) * (size_t)R + (size_t)(bR * 64 + ocolg);
        *(short8*)(dst + idx) = *(const short8*)&T[orow][ocolg];
    }
}

// ---------------- 64x64-tile GEMM v2: BK=64, dbuf, global_load_lds, XOR-swizzle ------
// C = (A@Bt^T + bias) * os. Two independent jobs selectable via blockIdx.z.
// LDS layout: As/Bs [2][64][64] bf16 LINEAR (global_load_lds writes base+lane*16).
// Swizzle: physical 16B colgrp = logical colgrp ^ (row&7) -- applied by permuting the
// GLOBAL source per lane on stage, and XOR-ing the ds_read address (rule: both sides).
struct GJ { const short* A; const short* B; const void* bias; void* C; float os; };

template<int OSRC>
__global__ __launch_bounds__(256)
void gemm64_bt_k(GJ j0, GJ j1, const int* __restrict__ dflag)
{
    __shared__ __align__(16) short As[2][64][64];
    __shared__ __align__(16) short Bs[2][64][64];

    const GJ j = blockIdx.z ? j1 : j0;
    const int rtf = *dflag;

    const int tid  = threadIdx.x;
    const int bN   = blockIdx.x, bM = blockIdx.y;
    const int lane = tid & 63, wave = tid >> 6;
    const int wm   = (wave >> 1) * 32;
    const int wn   = (wave & 1) * 32;
    const int quad = lane >> 4, r16 = lane & 15;

    floatx4 acc[2][2];
    #pragma unroll
    for (int i = 0; i < 2; ++i)
        #pragma unroll
        for (int jj = 0; jj < 2; ++jj)
            acc[i][jj] = (floatx4){0.f, 0.f, 0.f, 0.f};

    // staging geometry: instr jj of wave w covers tile rows [w*8 + jj*32, +8);
    // lane l -> row w*8+jj*32+(l>>3), phys colgrp l&7, logical colgrp (l&7)^((l>>3)&7)
    const int srow = wave * 8 + (lane >> 3);
    const int scg  = (lane & 7) ^ ((lane >> 3) & 7);
    const short* gA = j.A + (size_t)(bM * 64 + srow) * 1024 + scg * 8;
    const short* gB = j.B + (size_t)(bN * 64 + srow) * 1024 + scg * 8;

#define STAGE(buf, k0)                                                          \
    {                                                                           \
        _Pragma("unroll")                                                       \
        for (int jj = 0; jj < 2; ++jj) {                                        \
            GLOAD16(gA + (size_t)jj * 32 * 1024 + (k0),                         \
                    &As[buf][wave * 8 + jj * 32][0]);                           \
            GLOAD16(gB + (size_t)jj * 32 * 1024 + (k0),                         \
                    &Bs[buf][wave * 8 + jj * 32][0]);                           \
        }                                                                       \
    }

    STAGE(0, 0);
    __syncthreads();

    const int sr = r16 & 7;   // row&7 for all fragment rows (wm,wn,+16 are 0 mod 8)
    int buf = 0;
    for (int t = 0; t < 16; ++t) {
        if (t < 15) STAGE(buf ^ 1, (t + 1) * 64);
        #pragma unroll
        for (int kk = 0; kk < 2; ++kk) {
            const int pc = ((kk * 4 + quad) ^ sr) * 8;
            const short8 a0 = *(const short8*)&As[buf][wm + r16][pc];
            const short8 a1 = *(const short8*)&As[buf][wm + 16 + r16][pc];
            const short8 b0 = *(const short8*)&Bs[buf][wn + r16][pc];
            const short8 b1 = *(const short8*)&Bs[buf][wn + 16 + r16][pc];
            acc[0][0] = __builtin_amdgcn_mfma_f32_16x16x32_bf16(a0, b0, acc[0][0], 0, 0, 0);
            acc[0][1] = __builtin_amdgcn_mfma_f32_16x16x32_bf16(a0, b1, acc[0][1], 0, 0, 0);
            acc[1][0] = __builtin_amdgcn_mfma_f32_16x16x32_bf16(a1, b0, acc[1][0], 0, 0, 0);
            acc[1][1] = __builtin_amdgcn_mfma_f32_16x16x32_bf16(a1, b1, acc[1][1], 0, 0, 0);
        }
        __syncthreads();   // drains staged loads (issued before compute) + buf reuse
        buf ^= 1;
    }
#undef STAGE

    const bool of32 = (OSRC == SRC_F32) || (OSRC == SRC_RT && rtf);
    #pragma unroll
    for (int jj = 0; jj < 2; ++jj) {
        const int gc = bN * 64 + wn + jj * 16 + r16;
        const float bb = rtf ? ((const float*)j.bias)[gc]
                             : bf2f(((const unsigned short*)j.bias)[gc]);
        #pragma unroll
        for (int i = 0; i < 2; ++i) {
            #pragma unroll
            for (int rg = 0; rg < 4; ++rg) {
                const int gr = bM * 64 + wm + i * 16 + quad * 4 + rg;
                const float v = (acc[i][jj][rg] + bb) * j.os;
                if (of32)
                    ((float*)j.C)[(size_t)gr * 1024 + gc] = v;
                else
                    ((__hip_bfloat16*)j.C)[(size_t)gr * 1024 + gc] = __float2bfloat16(v);
            }
        }
    }
}

// ---------------- fused attention v6.1: lane-private candidate segments --------------
// Block = 16 Q-rows x 1 head, 256 threads (4 waves), LDS ~16.9 KB -> 8 blocks/CU.
// Wave w owns ALL 16 rows x column quarter w. K fragments direct from global (L2-hot).
// Barrier-free main loop. Per 256-col step: 8 MFMA -> top-2 fold -> atomicMax rmax ->
// per-lane keep test appending into the lane's PRIVATE 3-slot segment (overflow ->
// shared 64-slot region, rare). Q pre-scaled by 1/8 in the projection. Tail:
// sentinel-aware Michelot from tau0 = g1-1, ballot-compact, 8-deep sparse PV gather.
__global__ __launch_bounds__(256, 8)
void attn_fused_k(const short* __restrict__ Qb, const short* __restrict__ Kb,
                  const short* __restrict__ Vb, short* __restrict__ Ob)
{
    __shared__ unsigned cpk[16][CAPT];
    __shared__ unsigned rmax[16];
    __shared__ int cnt[16];

    const int tid  = threadIdx.x;
    const int lane = tid & 63, wave = tid >> 6;
    const int quad = lane >> 4, r16 = lane & 15;

    // head->XCD pinning: blocks with bid%8==x carry heads x and x+8.
    const int bid  = blockIdx.x;
    const int slot = bid >> 3;
    const int h    = (slot & 1) * 8 + (bid & 7);
    const int row0 = (slot >> 1) * 16;

    if (tid < 16) { rmax[tid] = fmap(-3.0e38f); cnt[tid] = 0; }
    __syncthreads();

    // Q fragment, direct from global (all 4 waves read the same 2 KB; L1-hot)
    const short* qp = Qb + (size_t)(row0 + r16) * 1024 + h * 64 + quad * 8;
    const short8 qa0 = *(const short8*)qp;
    const short8 qa1 = *(const short8*)(qp + 32);

    const int myrow = quad * 4;                // + rg
    const int wid   = wave * 16 + r16;         // writer id 0..63 (per row)
    const short* kp0 = Kb + (size_t)(wave * 16 + r16) * 1024 + h * 64 + quad * 8;

    // wave-local running top-2 per owned row (over this wave's column quarter)
    float rm1[4], rm2[4];
    int mycnt[4];
    #pragma unroll
    for (int rg = 0; rg < 4; ++rg) { rm1[rg] = -3.0e38f; rm2[rg] = -3.0e38f; mycnt[rg] = 0; }

    for (int s0 = 0; s0 < 2048; s0 += 256) {
        floatx4 acc[4];
        #pragma unroll
        for (int t = 0; t < 4; ++t) {
            const short* kp = kp0 + (size_t)(s0 + t * 64) * 1024;
            const short8 b0 = *(const short8*)kp;
            const short8 b1 = *(const short8*)(kp + 32);
            floatx4 a = (floatx4){0.f, 0.f, 0.f, 0.f};
            a = __builtin_amdgcn_mfma_f32_16x16x32_bf16(qa0, b0, a, 0, 0, 0);
            a = __builtin_amdgcn_mfma_f32_16x16x32_bf16(qa1, b1, a, 0, 0, 0);
            acc[t] = a;   // scale 1/8 pre-folded into Qb
        }

        // per-row tile top-2 fold (lane-local 4 vals, 16-lane butterfly), merge into
        // running top-2, post m1 to shared rmax (barrier-free; monotone)
        #pragma unroll
        for (int rg = 0; rg < 4; ++rg) {
            float m1ab = fmaxf(acc[0][rg], acc[1][rg]);
            float m2ab = fminf(acc[0][rg], acc[1][rg]);
            float m1cd = fmaxf(acc[2][rg], acc[3][rg]);
            float m2cd = fminf(acc[2][rg], acc[3][rg]);
            float m1 = fmaxf(m1ab, m1cd);
            float m2 = fmaxf(fminf(m1ab, m1cd), (m1ab >= m1cd) ? m2ab : m2cd);
            #pragma unroll
            for (int off = 1; off < 16; off <<= 1) {
                const float o1 = __shfl_xor(m1, off, 64);
                const float o2 = __shfl_xor(m2, off, 64);
                const float n2 = fmaxf(fminf(m1, o1), (m1 >= o1) ? m2 : o2);
                m1 = fmaxf(m1, o1);
                m2 = n2;
            }
            const float n1 = fmaxf(rm1[rg], m1);
            rm2[rg] = fmaxf(fminf(rm1[rg], m1), (rm1[rg] >= m1) ? rm2[rg] : m2);
            rm1[rg] = n1;
            if (r16 == 0) atomicMax(&rmax[myrow + rg], fmap(m1));
        }

        // lane-private append of candidates z >= thr (no ballots, no atomics except
        // rare overflow; any rmax read is a valid lower bound, own rm1 folded in)
        #pragma unroll
        for (int rg = 0; rg < 4; ++rg) {
            const int row = myrow + rg;
            const float g1 = fmaxf(funmap(rmax[row]), rm1[rg]);
            const float thr = fmaxf(g1 - 1.0f, 0.5f * (g1 + rm2[rg]) - 0.5f);
            #pragma unroll
            for (int t = 0; t < 4; ++t) {
                const float val = acc[t][rg];
                if (val >= thr) {
                    const unsigned pk = ((unsigned)f2bfu(val) << 16)
                                      | (unsigned)(s0 + wave * 16 + t * 64 + r16);
                    const int c = mycnt[rg];
                    if (c < NSEG) {
                        cpk[row][wid * NSEG + c] = pk;
                    } else {
                        const int p = atomicAdd(&cnt[row], 1);
                        if (p < OVF) cpk[row][64 * NSEG + p] = pk;
                    }
                    mycnt[rg] = c + 1;
                }
            }
        }
    }

    // sentinel-fill unused private slots (bf16 -inf packed)
    #pragma unroll
    for (int rg = 0; rg < 4; ++rg) {
        const int row = myrow + rg;
        for (int k = mycnt[rg]; k < NSEG; ++k)
            cpk[row][wid * NSEG + k] = 0xFF800000u;
    }
    __syncthreads();   // all appends visible

    // ---- per-wave Michelot + PV on owned rows (wave w: rows w*4 .. w*4+3) ----
    const unsigned long long pre = (1ULL << lane) - 1ULL;
    for (int rr = 0; rr < 4; ++rr) {
        const int r = wave * 4 + rr;
        const int novf = min(cnt[r], OVF);

        float v[4];
        unsigned short ii[4];
        #pragma unroll
        for (int i = 0; i < 3; ++i) {
            const unsigned u = cpk[r][lane + i * 64];
            v[i] = bf2f((unsigned short)(u >> 16));
            ii[i] = (unsigned short)(u & 0xFFFFu);
        }
        if (lane < novf) {
            const unsigned u = cpk[r][64 * NSEG + lane];
            v[3] = bf2f((unsigned short)(u >> 16));
            ii[3] = (unsigned short)(u & 0xFFFFu);
        } else { v[3] = -3.0e38f; ii[3] = 0; }

        // Michelot from valid lower bound tau0 = g1-1 (monotone increasing)
        float tau = funmap(rmax[r]) - 1.0f, prevc = -1.0f;
        for (int it = 0; it < 24; ++it) {
            float s = 0.f, c = 0.f;
            #pragma unroll
            for (int i = 0; i < 4; ++i)
                if (v[i] > tau) { s += v[i]; c += 1.f; }
            #pragma unroll
            for (int off = 1; off < 64; off <<= 1) {
                s += __shfl_xor(s, off, 64);
                c += __shfl_xor(c, off, 64);
            }
            if (c == prevc) break;
            prevc = c;
            tau = (s - 1.0f) / c;
        }

        // ballot-compact support (p>0) to list front, p packed bf16
        int base = 0;
        #pragma unroll
        for (int i = 0; i < 4; ++i) {
            const float p = v[i] - tau;
            const unsigned long long m = __ballot(p > 0.f);
            const int w = base + __popcll(m & pre);
            if (p > 0.f) cpk[r][w] = ((unsigned)f2bfu(p) << 16) | (unsigned)ii[i];
            base += __popcll(m);
        }
        const int msup = base;

        // sparse PV gather: lane = output col; 8-deep independent loads
        const unsigned short* vb = (const unsigned short*)Vb + (size_t)h * 64 + lane;
        float o0 = 0.f, o1 = 0.f, o2 = 0.f, o3 = 0.f;
        float o4 = 0.f, o5 = 0.f, o6 = 0.f, o7 = 0.f;
        int jj = 0;
        for (; jj + 8 <= msup; jj += 8) {
            const unsigned u0 = cpk[r][jj],     u1 = cpk[r][jj + 1];
            const unsigned u2 = cpk[r][jj + 2], u3 = cpk[r][jj + 3];
            const unsigned u4 = cpk[r][jj + 4], u5 = cpk[r][jj + 5];
            const unsigned u6 = cpk[r][jj + 6], u7 = cpk[r][jj + 7];
            o0 += bf2f((unsigned short)(u0 >> 16)) * bf2f(vb[(size_t)(u0 & 0xFFFFu) * 1024]);
            o1 += bf2f((unsigned short)(u1 >> 16)) * bf2f(vb[(size_t)(u1 & 0xFFFFu) * 1024]);
            o2 += bf2f((unsigned short)(u2 >> 16)) * bf2f(vb[(size_t)(u2 & 0xFFFFu) * 1024]);
            o3 += bf2f((unsigned short)(u3 >> 16)) * bf2f(vb[(size_t)(u3 & 0xFFFFu) * 1024]);
            o4 += bf2f((unsigned short)(u4 >> 16)) * bf2f(vb[(size_t)(u4 & 0xFFFFu) * 1024]);
            o5 += bf2f((unsigned short)(u5 >> 16)) * bf2f(vb[(size_t)(u5 & 0xFFFFu) * 1024]);
            o6 += bf2f((unsigned short)(u6 >> 16)) * bf2f(vb[(size_t)(u6 & 0xFFFFu) * 1024]);
            o7 += bf2f((unsigned short)(u7 >> 16)) * bf2f(vb[(size_t)(u7 & 0xFFFFu) * 1024]);
        }
        for (; jj < msup; ++jj) {
            const unsigned u0 = cpk[r][jj];
            o0 += bf2f((unsigned short)(u0 >> 16)) * bf2f(vb[(size_t)(u0 & 0xFFFFu) * 1024]);
        }
        const float out = ((o0 + o1) + (o2 + o3)) + ((o4 + o5) + (o6 + o7));
        Ob[((size_t)h * 2048 + row0 + r) * 64 + lane] = f2bf(out);
    }
}

extern "C" void kernel_launch(void* const* d_in, const int* in_sizes, int n_in,
                              void* d_out, int out_size, void* d_ws, size_t ws_size,
                              hipStream_t stream)
{
    (void)in_sizes; (void)n_in; (void)out_size; (void)ws_size;

    const void* queries = d_in[0];
    const void* keys    = d_in[1];
    // d_in[2] ("values") unused by the reference.
    const void* Wq = d_in[3];
    const void* bq = d_in[4];
    const void* Wk = d_in[5];
    const void* bk = d_in[6];
    const void* Wv = d_in[7];
    const void* bv = d_in[8];
    const void* Wo = d_in[9];
    const void* bo = d_in[10];

    const int L = 2048, DM = 1024;
    const size_t LD = (size_t)L * DM;   // 2M elements

    int*   flag = (int*)d_ws;
    short* Qc  = (short*)((char*)d_ws + 256);  // bf16 queries      [2048,1024]
    short* Kc  = Qc + LD;                      // bf16 keys         [2048,1024]
    short* WqT = Kc + LD;                      // bf16 Wq^T         [1024,1024]
    short* WkT = WqT + (size_t)DM * DM;
    short* WvT = WkT + (size_t)DM * DM;
    short* WoT = WvT + (size_t)DM * DM;
    short* Qb  = WoT + (size_t)DM * DM;        // [2048,1024] (pre-scaled by 1/8)
    short* Kb  = Qb + LD;
    short* Vb  = Kb + LD;
    short* Ob  = Vb + LD;                      // [H,2048,64] contiguous (== mixed view)

    dim3 blk(256);

    // 0) dtype detection
    detect_k<<<dim3(1), dim3(64), 0, stream>>>((const short*)queries, 4096, flag);

    // p1) convert queries/keys -> bf16
    convert2_k<<<dim3((unsigned)(LD / 2048), 1, 2), blk, 0, stream>>>(
        queries, keys, Qc, Kc, flag);

    // p2) transpose-convert the 4 weight matrices -> bf16 [N][K]
    {
        TP4 p;
        p.s[0] = Wq; p.s[1] = Wk; p.s[2] = Wv; p.s[3] = Wo;
        p.d[0] = WqT; p.d[1] = WkT; p.d[2] = WvT; p.d[3] = WoT;
        transpose4_k<<<dim3(DM / 64, DM / 64, 4), blk, 0, stream>>>(p, DM, DM, flag);
    }

    // 1) Qb & Kb projections batched (Q job pre-scales by 1/8; exact pow2)
    {
        GJ jq{(const short*)Qc, WqT, bq, Qb, 0.125f};
        GJ jk{(const short*)Kc, WkT, bk, Kb, 1.0f};
        gemm64_bt_k<SRC_BF16><<<dim3(DM / 64, L / 64, 2), blk, 0, stream>>>(jq, jk, flag);
    }
    // 2) Vb = Kb @ WvT + bv   (reference quirk: V from key projection)
    {
        GJ jv{(const short*)Kb, WvT, bv, Vb, 1.0f};
        gemm64_bt_k<SRC_BF16><<<dim3(DM / 64, L / 64, 1), blk, 0, stream>>>(jv, jv, flag);
    }

    // 3) fused attention (scores never reach HBM; barrier-free main loop)
    attn_fused_k<<<dim3((L / 16) * 16), blk, 0, stream>>>(Qb, Kb, Vb, Ob);

    // 4) out = Ob(viewed [2048,1024]) @ WoT + bo -> d_out (dtype per flag)
    {
        GJ jo{(const short*)Ob, WoT, bo, d_out, 1.0f};
        gemm64_bt_k<SRC_RT><<<dim3(DM / 64, L / 64, 1), blk, 0, stream>>>(jo, jo, flag);
    }
}

// Round 7
// 264.931 us; speedup vs baseline: 1.0561x; 1.0155x over previous
//
#include <hip/hip_runtime.h>
#include <hip/hip_bf16.h>

// Hopfield sparsemax attention, MI355X gfx950.
// B=1, L=S=2048, D_MODEL=1024, H=16, DK=64. Inputs fp32 (runtime-detected), output per flag.
//
// Round-16 (bisect after R15 correctness failure):
//   - attn MAIN LOOP reverted byte-identical to R13/v6.1 (last PASSING version):
//     per-256-step MFMA -> top-2 fold -> per-step atomicMax rmax -> lane-private append
//     with thr = max(g1-1, (g1+m2-1)/2), scalar sentinel fill of private slots.
//   - ONLY new piece: row-parallel tail. Quad q of wave w owns row 4w+q (16 rows
//     concurrent, was 4 sequential rows per wave). 16 candidates/lane; overflow slots
//     (k>=12) guarded by cnt[r] in REGISTERS (no memory sentinels, no uint4 init).
//     Michelot: 4-stage quad butterfly (was 6-stage x4 rows). Quad-ballot compact.
//     PV: uint2 loads, 4 output cols/lane.
//   GEMM v2 (BK=64, dbuf, global_load_lds, XOR-swizzle) and rest unchanged from R13.

typedef __attribute__((ext_vector_type(8))) short short8;
typedef __attribute__((ext_vector_type(4))) float floatx4;

#define SRC_BF16 0
#define SRC_F32  1
#define SRC_RT   2
#define NSEG 3            // private slots per writer lane
#define OVF 64            // shared overflow slots per row
#define CAPT (64 * NSEG + OVF)   // 256 u32 per row

typedef __attribute__((address_space(1))) const void GAS;
typedef __attribute__((address_space(3))) void LAS;
#define GLOAD16(g, l) __builtin_amdgcn_global_load_lds((GAS*)(g), (LAS*)(l), 16, 0, 0)

__device__ __forceinline__ short f2bf(float f) {
    __hip_bfloat16 h = __float2bfloat16(f);
    return *reinterpret_cast<const short*>(&h);
}
__device__ __forceinline__ unsigned short f2bfu(float f) {
    __hip_bfloat16 h = __float2bfloat16(f);
    return *reinterpret_cast<const unsigned short*>(&h);
}
__device__ __forceinline__ float bf2f(unsigned short u) {
    return __uint_as_float(((unsigned)u) << 16);
}
// monotone float->uint map (order-preserving for all finite floats)
__device__ __forceinline__ unsigned fmap(float f) {
    unsigned u = __float_as_uint(f);
    return (u & 0x80000000u) ? ~u : (u | 0x80000000u);
}
__device__ __forceinline__ float funmap(unsigned u) {
    return (u & 0x80000000u) ? __uint_as_float(u ^ 0x80000000u) : __uint_as_float(~u);
}

// Detect input dtype: decode first n shorts as bf16; fp32-read-as-bf16 almost surely
// yields |x|>1e10 / inf / NaN. One 64-thread block.
__global__ void detect_k(const short* __restrict__ q, int n, int* __restrict__ flag)
{
    const int tid = threadIdx.x;
    int bad = 0;
    for (int i = tid; i < n; i += 64) {
        float f = bf2f((unsigned short)q[i]);
        if (!(fabsf(f) < 1e10f)) bad = 1;
    }
    unsigned long long m = __ballot(bad != 0);
    if (tid == 0) *flag = (m != 0ULL) ? 1 : 0;
}

// Flat convert (fp32|bf16 per flag) -> bf16. z selects one of two sources.
__global__ __launch_bounds__(256)
void convert2_k(const void* __restrict__ s0, const void* __restrict__ s1,
                short* __restrict__ d0, short* __restrict__ d1,
                const int* __restrict__ dflag)
{
    const void* s = blockIdx.z ? s1 : s0;
    short* d = blockIdx.z ? d1 : d0;
    const size_t i = ((size_t)blockIdx.x * 256 + threadIdx.x) * 8;
    short8 o;
    if (*dflag) {
        const float4 f0 = ((const float4*)((const float*)s + i))[0];
        const float4 f1 = ((const float4*)((const float*)s + i))[1];
        o[0] = f2bf(f0.x); o[1] = f2bf(f0.y); o[2] = f2bf(f0.z); o[3] = f2bf(f0.w);
        o[4] = f2bf(f1.x); o[5] = f2bf(f1.y); o[6] = f2bf(f1.z); o[7] = f2bf(f1.w);
    } else {
        o = *(const short8*)((const short*)s + i);
    }
    *(short8*)(d + i) = o;
}

// Batched weight transpose: 4 matrices [R,C] -> bf16 [C,R], selected by blockIdx.z.
struct TP4 {
    const void* s[4];
    short* d[4];
};
__global__ __launch_bounds__(256)
void transpose4_k(TP4 p, int R, int C, const int* __restrict__ dflag)
{
    __shared__ short T[64][72];
    const int tid = threadIdx.x;
    const int bC = blockIdx.x, bR = blockIdx.y;
    const void* src = p.s[blockIdx.z];
    short* dst = p.d[blockIdx.z];
    const bool f32 = (*dflag != 0);

    const int colg = (tid & 7) * 8;
    #pragma unroll
    for (int h = 0; h < 2; ++h) {
        const int row = (tid >> 3) + 32 * h;
        const size_t idx = (size_t)(bR * 64 + row) * (size_t)C + (size_t)(bC * 64 + colg);
        short e[8];
        if (f32) {
            const float4 f0 = ((const float4*)((const float*)src + idx))[0];
            const float4 f1 = ((const float4*)((const float*)src + idx))[1];
            e[0] = f2bf(f0.x); e[1] = f2bf(f0.y); e[2] = f2bf(f0.z); e[3] = f2bf(f0.w);
            e[4] = f2bf(f1.x); e[5] = f2bf(f1.y); e[6] = f2bf(f1.z); e[7] = f2bf(f1.w);
        } else {
            short8 s = *(const short8*)((const short*)src + idx);
            #pragma unroll
            for (int j = 0; j < 8; ++j) e[j] = s[j];
        }
        #pragma unroll
        for (int j = 0; j < 8; ++j) T[colg + j][row] = e[j];
    }
    __syncthreads();
    #pragma unroll
    for (int h = 0; h < 2; ++h) {
        const int orow = (tid >> 3) + 32 * h;
        const int ocolg = (tid & 7) * 8;
        const size_t idx = (size_t)(bC * 64 + orow) * (size_t)R + (size_t)(bR * 64 + ocolg);
        *(short8*)(dst + idx) = *(const short8*)&T[orow][ocolg];
    }
}

// ---------------- 64x64-tile GEMM v2: BK=64, dbuf, global_load_lds, XOR-swizzle ------
// C = (A@Bt^T + bias) * os. Two independent jobs selectable via blockIdx.z.
struct GJ { const short* A; const short* B; const void* bias; void* C; float os; };

template<int OSRC>
__global__ __launch_bounds__(256)
void gemm64_bt_k(GJ j0, GJ j1, const int* __restrict__ dflag)
{
    __shared__ __align__(16) short As[2][64][64];
    __shared__ __align__(16) short Bs[2][64][64];

    const GJ j = blockIdx.z ? j1 : j0;
    const int rtf = *dflag;

    const int tid  = threadIdx.x;
    const int bN   = blockIdx.x, bM = blockIdx.y;
    const int lane = tid & 63, wave = tid >> 6;
    const int wm   = (wave >> 1) * 32;
    const int wn   = (wave & 1) * 32;
    const int quad = lane >> 4, r16 = lane & 15;

    floatx4 acc[2][2];
    #pragma unroll
    for (int i = 0; i < 2; ++i)
        #pragma unroll
        for (int jj = 0; jj < 2; ++jj)
            acc[i][jj] = (floatx4){0.f, 0.f, 0.f, 0.f};

    const int srow = wave * 8 + (lane >> 3);
    const int scg  = (lane & 7) ^ ((lane >> 3) & 7);
    const short* gA = j.A + (size_t)(bM * 64 + srow) * 1024 + scg * 8;
    const short* gB = j.B + (size_t)(bN * 64 + srow) * 1024 + scg * 8;

#define STAGE(buf, k0)                                                          \
    {                                                                           \
        _Pragma("unroll")                                                       \
        for (int jj = 0; jj < 2; ++jj) {                                        \
            GLOAD16(gA + (size_t)jj * 32 * 1024 + (k0),                         \
                    &As[buf][wave * 8 + jj * 32][0]);                           \
            GLOAD16(gB + (size_t)jj * 32 * 1024 + (k0),                         \
                    &Bs[buf][wave * 8 + jj * 32][0]);                           \
        }                                                                       \
    }

    STAGE(0, 0);
    __syncthreads();

    const int sr = r16 & 7;
    int buf = 0;
    for (int t = 0; t < 16; ++t) {
        if (t < 15) STAGE(buf ^ 1, (t + 1) * 64);
        #pragma unroll
        for (int kk = 0; kk < 2; ++kk) {
            const int pc = ((kk * 4 + quad) ^ sr) * 8;
            const short8 a0 = *(const short8*)&As[buf][wm + r16][pc];
            const short8 a1 = *(const short8*)&As[buf][wm + 16 + r16][pc];
            const short8 b0 = *(const short8*)&Bs[buf][wn + r16][pc];
            const short8 b1 = *(const short8*)&Bs[buf][wn + 16 + r16][pc];
            acc[0][0] = __builtin_amdgcn_mfma_f32_16x16x32_bf16(a0, b0, acc[0][0], 0, 0, 0);
            acc[0][1] = __builtin_amdgcn_mfma_f32_16x16x32_bf16(a0, b1, acc[0][1], 0, 0, 0);
            acc[1][0] = __builtin_amdgcn_mfma_f32_16x16x32_bf16(a1, b0, acc[1][0], 0, 0, 0);
            acc[1][1] = __builtin_amdgcn_mfma_f32_16x16x32_bf16(a1, b1, acc[1][1], 0, 0, 0);
        }
        __syncthreads();
        buf ^= 1;
    }
#undef STAGE

    const bool of32 = (OSRC == SRC_F32) || (OSRC == SRC_RT && rtf);
    #pragma unroll
    for (int jj = 0; jj < 2; ++jj) {
        const int gc = bN * 64 + wn + jj * 16 + r16;
        const float bb = rtf ? ((const float*)j.bias)[gc]
                             : bf2f(((const unsigned short*)j.bias)[gc]);
        #pragma unroll
        for (int i = 0; i < 2; ++i) {
            #pragma unroll
            for (int rg = 0; rg < 4; ++rg) {
                const int gr = bM * 64 + wm + i * 16 + quad * 4 + rg;
                const float v = (acc[i][jj][rg] + bb) * j.os;
                if (of32)
                    ((float*)j.C)[(size_t)gr * 1024 + gc] = v;
                else
                    ((__hip_bfloat16*)j.C)[(size_t)gr * 1024 + gc] = __float2bfloat16(v);
            }
        }
    }
}

// ---------------- fused attention v6.2: v6.1 main loop + row-parallel tail -----------
// Block = 16 Q-rows x 1 head, 256 threads (4 waves), LDS ~16.2 KB -> 8 blocks/CU.
// MAIN LOOP identical to v6.1 (R13, passing): per 256-col step, 8 MFMA -> top-2 fold
// (m1,m2) -> per-step atomicMax rmax (barrier-free, monotone) -> lane-private append
// with thr = max(g1-1, (g1+m2-1)/2) <= tau. Scalar sentinel fill of private slots.
// NEW TAIL: quad q of wave w owns row 4w+q (16 rows concurrent). 16 candidates/lane;
// overflow (k>=12) guarded by cnt[r] in registers. Michelot from tau0 = g1-1 (4-stage
// quad butterfly), quad-ballot compact, uint2 PV with 4 output cols/lane.
__global__ __launch_bounds__(256, 8)
void attn_fused_k(const short* __restrict__ Qb, const short* __restrict__ Kb,
                  const short* __restrict__ Vb, short* __restrict__ Ob)
{
    __shared__ unsigned cpk[16][CAPT];
    __shared__ unsigned rmax[16];
    __shared__ int cnt[16];

    const int tid  = threadIdx.x;
    const int lane = tid & 63, wave = tid >> 6;
    const int quad = lane >> 4, r16 = lane & 15;

    // head->XCD pinning: blocks with bid%8==x carry heads x and x+8.
    const int bid  = blockIdx.x;
    const int slot = bid >> 3;
    const int h    = (slot & 1) * 8 + (bid & 7);
    const int row0 = (slot >> 1) * 16;

    if (tid < 16) { rmax[tid] = fmap(-3.0e38f); cnt[tid] = 0; }
    __syncthreads();

    // Q fragment, direct from global (all 4 waves read the same 2 KB; L1-hot)
    const short* qp = Qb + (size_t)(row0 + r16) * 1024 + h * 64 + quad * 8;
    const short8 qa0 = *(const short8*)qp;
    const short8 qa1 = *(const short8*)(qp + 32);

    const int myrow = quad * 4;                // + rg
    const int wid   = wave * 16 + r16;         // writer id 0..63 (per row)
    const short* kp0 = Kb + (size_t)(wave * 16 + r16) * 1024 + h * 64 + quad * 8;

    // wave-local running top-2 per owned row (over this wave's column quarter)
    float rm1[4], rm2[4];
    int mycnt[4];
    #pragma unroll
    for (int rg = 0; rg < 4; ++rg) { rm1[rg] = -3.0e38f; rm2[rg] = -3.0e38f; mycnt[rg] = 0; }

    for (int s0 = 0; s0 < 2048; s0 += 256) {
        floatx4 acc[4];
        #pragma unroll
        for (int t = 0; t < 4; ++t) {
            const short* kp = kp0 + (size_t)(s0 + t * 64) * 1024;
            const short8 b0 = *(const short8*)kp;
            const short8 b1 = *(const short8*)(kp + 32);
            floatx4 a = (floatx4){0.f, 0.f, 0.f, 0.f};
            a = __builtin_amdgcn_mfma_f32_16x16x32_bf16(qa0, b0, a, 0, 0, 0);
            a = __builtin_amdgcn_mfma_f32_16x16x32_bf16(qa1, b1, a, 0, 0, 0);
            acc[t] = a;   // scale 1/8 pre-folded into Qb
        }

        // per-row tile top-2 fold (lane-local 4 vals, 16-lane butterfly), merge into
        // running top-2, post m1 to shared rmax (barrier-free; monotone)
        #pragma unroll
        for (int rg = 0; rg < 4; ++rg) {
            float m1ab = fmaxf(acc[0][rg], acc[1][rg]);
            float m2ab = fminf(acc[0][rg], acc[1][rg]);
            float m1cd = fmaxf(acc[2][rg], acc[3][rg]);
            float m2cd = fminf(acc[2][rg], acc[3][rg]);
            float m1 = fmaxf(m1ab, m1cd);
            float m2 = fmaxf(fminf(m1ab, m1cd), (m1ab >= m1cd) ? m2ab : m2cd);
            #pragma unroll
            for (int off = 1; off < 16; off <<= 1) {
                const float o1 = __shfl_xor(m1, off, 64);
                const float o2 = __shfl_xor(m2, off, 64);
                const float n2 = fmaxf(fminf(m1, o1), (m1 >= o1) ? m2 : o2);
                m1 = fmaxf(m1, o1);
                m2 = n2;
            }
            const float n1 = fmaxf(rm1[rg], m1);
            rm2[rg] = fmaxf(fminf(rm1[rg], m1), (rm1[rg] >= m1) ? rm2[rg] : m2);
            rm1[rg] = n1;
            if (r16 == 0) atomicMax(&rmax[myrow + rg], fmap(m1));
        }

        // lane-private append of candidates z >= thr (no ballots, no atomics except
        // rare overflow; any rmax read is a valid lower bound, own rm1 folded in)
        #pragma unroll
        for (int rg = 0; rg < 4; ++rg) {
            const int row = myrow + rg;
            const float g1 = fmaxf(funmap(rmax[row]), rm1[rg]);
            const float thr = fmaxf(g1 - 1.0f, 0.5f * (g1 + rm2[rg]) - 0.5f);
            #pragma unroll
            for (int t = 0; t < 4; ++t) {
                const float val = acc[t][rg];
                if (val >= thr) {
                    const unsigned pk = ((unsigned)f2bfu(val) << 16)
                                      | (unsigned)(s0 + wave * 16 + t * 64 + r16);
                    const int c = mycnt[rg];
                    if (c < NSEG) {
                        cpk[row][wid * NSEG + c] = pk;
                    } else {
                        const int p = atomicAdd(&cnt[row], 1);
                        if (p < OVF) cpk[row][64 * NSEG + p] = pk;
                    }
                    mycnt[rg] = c + 1;
                }
            }
        }
    }

    // sentinel-fill unused private slots (bf16 -inf packed)
    #pragma unroll
    for (int rg = 0; rg < 4; ++rg) {
        const int row = myrow + rg;
        for (int k = mycnt[rg]; k < NSEG; ++k)
            cpk[row][wid * NSEG + k] = 0xFF800000u;
    }
    __syncthreads();   // all appends + final rmax visible

    // ---- row-parallel tail: quad q of wave w owns row 4w+q ----
    const int r = wave * 4 + quad;
    const int novf = min(cnt[r], OVF);

    // 16 candidates per lane; k>=12 are overflow slots, guarded by novf
    unsigned ca[16];
    #pragma unroll
    for (int k = 0; k < 12; ++k) ca[k] = cpk[r][k * 16 + r16];
    #pragma unroll
    for (int k = 12; k < 16; ++k) {
        const int oi = k * 16 + r16 - 64 * NSEG;
        ca[k] = (oi < novf) ? cpk[r][k * 16 + r16] : 0xFF800000u;
    }

    // Michelot from exact tau0 = g1-1 (monotone increasing; sentinels never activate)
    float tau = funmap(rmax[r]) - 1.0f;
    float prevc = -1.0f;
    for (int it = 0; it < 18; ++it) {
        float s = 0.f, c = 0.f;
        #pragma unroll
        for (int k = 0; k < 16; ++k) {
            const float v = __uint_as_float(ca[k] & 0xFFFF0000u);
            if (v > tau) { s += v; c += 1.f; }
        }
        #pragma unroll
        for (int off = 1; off < 16; off <<= 1) {
            s += __shfl_xor(s, off, 64);
            c += __shfl_xor(c, off, 64);
        }
        if (c == prevc || c == 0.f) break;
        prevc = c;
        tau = (s - 1.0f) / c;
    }

    // quad-ballot compact of support (p>0) to list front, p packed bf16
    const unsigned qpre = (1u << r16) - 1u;
    int base = 0;
    #pragma unroll
    for (int k = 0; k < 16; ++k) {
        const float v = __uint_as_float(ca[k] & 0xFFFF0000u);
        const float p = v - tau;
        const bool keep = (p > 0.f);
        const unsigned long long mm = __ballot(keep);
        const unsigned qm = (unsigned)((mm >> (quad * 16)) & 0xFFFFull);
        if (keep)
            cpk[r][base + __popc(qm & qpre)] =
                ((unsigned)f2bfu(p) << 16) | (ca[k] & 0xFFFFu);
        base += __popc(qm);
    }
    const int msup = base;

    // PV gather: lane covers out cols r16*4..+3 (uint2); rows parallel across quads
    const unsigned short* vb = (const unsigned short*)Vb + (size_t)h * 64 + r16 * 4;
    float o0 = 0.f, o1 = 0.f, o2 = 0.f, o3 = 0.f;
    int jj = 0;
    for (; jj + 2 <= msup; jj += 2) {
        const unsigned ua = cpk[r][jj], ub = cpk[r][jj + 1];
        const float pa = __uint_as_float(ua & 0xFFFF0000u);
        const float pb = __uint_as_float(ub & 0xFFFF0000u);
        const uint2 da = *(const uint2*)(vb + (size_t)(ua & 0xFFFFu) * 1024);
        const uint2 db = *(const uint2*)(vb + (size_t)(ub & 0xFFFFu) * 1024);
        o0 += pa * __uint_as_float(da.x << 16);
        o1 += pa * __uint_as_float(da.x & 0xFFFF0000u);
        o2 += pa * __uint_as_float(da.y << 16);
        o3 += pa * __uint_as_float(da.y & 0xFFFF0000u);
        o0 += pb * __uint_as_float(db.x << 16);
        o1 += pb * __uint_as_float(db.x & 0xFFFF0000u);
        o2 += pb * __uint_as_float(db.y << 16);
        o3 += pb * __uint_as_float(db.y & 0xFFFF0000u);
    }
    if (jj < msup) {
        const unsigned ua = cpk[r][jj];
        const float pa = __uint_as_float(ua & 0xFFFF0000u);
        const uint2 da = *(const uint2*)(vb + (size_t)(ua & 0xFFFFu) * 1024);
        o0 += pa * __uint_as_float(da.x << 16);
        o1 += pa * __uint_as_float(da.x & 0xFFFF0000u);
        o2 += pa * __uint_as_float(da.y << 16);
        o3 += pa * __uint_as_float(da.y & 0xFFFF0000u);
    }

    short* op = Ob + ((size_t)h * 2048 + row0 + r) * 64 + r16 * 4;
    op[0] = f2bf(o0); op[1] = f2bf(o1); op[2] = f2bf(o2); op[3] = f2bf(o3);
}

extern "C" void kernel_launch(void* const* d_in, const int* in_sizes, int n_in,
                              void* d_out, int out_size, void* d_ws, size_t ws_size,
                              hipStream_t stream)
{
    (void)in_sizes; (void)n_in; (void)out_size; (void)ws_size;

    const void* queries = d_in[0];
    const void* keys    = d_in[1];
    // d_in[2] ("values") unused by the reference.
    const void* Wq = d_in[3];
    const void* bq = d_in[4];
    const void* Wk = d_in[5];
    const void* bk = d_in[6];
    const void* Wv = d_in[7];
    const void* bv = d_in[8];
    const void* Wo = d_in[9];
    const void* bo = d_in[10];

    const int L = 2048, DM = 1024;
    const size_t LD = (size_t)L * DM;   // 2M elements

    int*   flag = (int*)d_ws;
    short* Qc  = (short*)((char*)d_ws + 256);  // bf16 queries      [2048,1024]
    short* Kc  = Qc + LD;                      // bf16 keys         [2048,1024]
    short* WqT = Kc + LD;                      // bf16 Wq^T         [1024,1024]
    short* WkT = WqT + (size_t)DM * DM;
    short* WvT = WkT + (size_t)DM * DM;
    short* WoT = WvT + (size_t)DM * DM;
    short* Qb  = WoT + (size_t)DM * DM;        // [2048,1024] (pre-scaled by 1/8)
    short* Kb  = Qb + LD;
    short* Vb  = Kb + LD;
    short* Ob  = Vb + LD;                      // [H,2048,64] contiguous (== mixed view)

    dim3 blk(256);

    // 0) dtype detection
    detect_k<<<dim3(1), dim3(64), 0, stream>>>((const short*)queries, 4096, flag);

    // p1) convert queries/keys -> bf16
    convert2_k<<<dim3((unsigned)(LD / 2048), 1, 2), blk, 0, stream>>>(
        queries, keys, Qc, Kc, flag);

    // p2) transpose-convert the 4 weight matrices -> bf16 [N][K]
    {
        TP4 p;
        p.s[0] = Wq; p.s[1] = Wk; p.s[2] = Wv; p.s[3] = Wo;
        p.d[0] = WqT; p.d[1] = WkT; p.d[2] = WvT; p.d[3] = WoT;
        transpose4_k<<<dim3(DM / 64, DM / 64, 4), blk, 0, stream>>>(p, DM, DM, flag);
    }

    // 1) Qb & Kb projections batched (Q job pre-scales by 1/8; exact pow2)
    {
        GJ jq{(const short*)Qc, WqT, bq, Qb, 0.125f};
        GJ jk{(const short*)Kc, WkT, bk, Kb, 1.0f};
        gemm64_bt_k<SRC_BF16><<<dim3(DM / 64, L / 64, 2), blk, 0, stream>>>(jq, jk, flag);
    }
    // 2) Vb = Kb @ WvT + bv   (reference quirk: V from key projection)
    {
        GJ jv{(const short*)Kb, WvT, bv, Vb, 1.0f};
        gemm64_bt_k<SRC_BF16><<<dim3(DM / 64, L / 64, 1), blk, 0, stream>>>(jv, jv, flag);
    }

    // 3) fused attention (scores never reach HBM; barrier-free main loop)
    attn_fused_k<<<dim3((L / 16) * 16), blk, 0, stream>>>(Qb, Kb, Vb, Ob);

    // 4) out = Ob(viewed [2048,1024]) @ WoT + bo -> d_out (dtype per flag)
    {
        GJ jo{(const short*)Ob, WoT, bo, d_out, 1.0f};
        gemm64_bt_k<SRC_RT><<<dim3(DM / 64, L / 64, 1), blk, 0, stream>>>(jo, jo, flag);
    }
}

// Round 8
// 232.363 us; speedup vs baseline: 1.2041x; 1.1402x over previous
//
#include <hip/hip_runtime.h>
#include <hip/hip_bf16.h>

// Hopfield sparsemax attention, MI355X gfx950.
// B=1, L=S=2048, D_MODEL=1024, H=16, DK=64. Inputs fp32 (runtime-detected), output per flag.
//
// Round-17 (attn v8: swapped-operand main loop -- reduction axis lane-local):
//   - QK^T computed as mfma(A=K-frag, B=Q-frag) => lane holds S[kc=quad*4+reg][qrow=r16]:
//     all 16 per-step values belong to the lane's OWN Q-row r16.
//   - Row top-2 fold: 16 lane-local merges + 2 cross-quad shuffle stages (off 16,32)
//     for ALL 16 rows at once (was 4x 4-stage butterflies per step).
//   - rmax post: one 16-lane-parallel atomicMax per step (distinct banks).
//   - Append: writer wid = wave*4+quad (16 writers/row x NSEG=12 private slots + 64
//     overflow = same 192+64 layout the R16 tail reads unchanged).
//   - cpk rows padded to 257 u32 -> tail stride-16 reads stop aliasing banks.
//   - Threshold semantics identical to R16: thr = max(g1-1, (g1+m2-1)/2) <= tau.
//   Tail (row-parallel Michelot+PV) byte-identical to R16. GEMM v2 and rest unchanged.

typedef __attribute__((ext_vector_type(8))) short short8;
typedef __attribute__((ext_vector_type(4))) float floatx4;

#define SRC_BF16 0
#define SRC_F32  1
#define SRC_RT   2
#define NSEG 12           // private slots per writer lane (16 writers/row)
#define OVF 64            // shared overflow slots per row
#define OVBASE 192        // 16 * NSEG
#define CAPP 257          // padded row stride (256 slots + 1 pad)

typedef __attribute__((address_space(1))) const void GAS;
typedef __attribute__((address_space(3))) void LAS;
#define GLOAD16(g, l) __builtin_amdgcn_global_load_lds((GAS*)(g), (LAS*)(l), 16, 0, 0)

__device__ __forceinline__ short f2bf(float f) {
    __hip_bfloat16 h = __float2bfloat16(f);
    return *reinterpret_cast<const short*>(&h);
}
__device__ __forceinline__ unsigned short f2bfu(float f) {
    __hip_bfloat16 h = __float2bfloat16(f);
    return *reinterpret_cast<const unsigned short*>(&h);
}
__device__ __forceinline__ float bf2f(unsigned short u) {
    return __uint_as_float(((unsigned)u) << 16);
}
// monotone float->uint map (order-preserving for all finite floats)
__device__ __forceinline__ unsigned fmap(float f) {
    unsigned u = __float_as_uint(f);
    return (u & 0x80000000u) ? ~u : (u | 0x80000000u);
}
__device__ __forceinline__ float funmap(unsigned u) {
    return (u & 0x80000000u) ? __uint_as_float(u ^ 0x80000000u) : __uint_as_float(~u);
}

// Detect input dtype: decode first n shorts as bf16; fp32-read-as-bf16 almost surely
// yields |x|>1e10 / inf / NaN. One 64-thread block.
__global__ void detect_k(const short* __restrict__ q, int n, int* __restrict__ flag)
{
    const int tid = threadIdx.x;
    int bad = 0;
    for (int i = tid; i < n; i += 64) {
        float f = bf2f((unsigned short)q[i]);
        if (!(fabsf(f) < 1e10f)) bad = 1;
    }
    unsigned long long m = __ballot(bad != 0);
    if (tid == 0) *flag = (m != 0ULL) ? 1 : 0;
}

// Flat convert (fp32|bf16 per flag) -> bf16. z selects one of two sources.
__global__ __launch_bounds__(256)
void convert2_k(const void* __restrict__ s0, const void* __restrict__ s1,
                short* __restrict__ d0, short* __restrict__ d1,
                const int* __restrict__ dflag)
{
    const void* s = blockIdx.z ? s1 : s0;
    short* d = blockIdx.z ? d1 : d0;
    const size_t i = ((size_t)blockIdx.x * 256 + threadIdx.x) * 8;
    short8 o;
    if (*dflag) {
        const float4 f0 = ((const float4*)((const float*)s + i))[0];
        const float4 f1 = ((const float4*)((const float*)s + i))[1];
        o[0] = f2bf(f0.x); o[1] = f2bf(f0.y); o[2] = f2bf(f0.z); o[3] = f2bf(f0.w);
        o[4] = f2bf(f1.x); o[5] = f2bf(f1.y); o[6] = f2bf(f1.z); o[7] = f2bf(f1.w);
    } else {
        o = *(const short8*)((const short*)s + i);
    }
    *(short8*)(d + i) = o;
}

// Batched weight transpose: 4 matrices [R,C] -> bf16 [C,R], selected by blockIdx.z.
struct TP4 {
    const void* s[4];
    short* d[4];
};
__global__ __launch_bounds__(256)
void transpose4_k(TP4 p, int R, int C, const int* __restrict__ dflag)
{
    __shared__ short T[64][72];
    const int tid = threadIdx.x;
    const int bC = blockIdx.x, bR = blockIdx.y;
    const void* src = p.s[blockIdx.z];
    short* dst = p.d[blockIdx.z];
    const bool f32 = (*dflag != 0);

    const int colg = (tid & 7) * 8;
    #pragma unroll
    for (int h = 0; h < 2; ++h) {
        const int row = (tid >> 3) + 32 * h;
        const size_t idx = (size_t)(bR * 64 + row) * (size_t)C + (size_t)(bC * 64 + colg);
        short e[8];
        if (f32) {
            const float4 f0 = ((const float4*)((const float*)src + idx))[0];
            const float4 f1 = ((const float4*)((const float*)src + idx))[1];
            e[0] = f2bf(f0.x); e[1] = f2bf(f0.y); e[2] = f2bf(f0.z); e[3] = f2bf(f0.w);
            e[4] = f2bf(f1.x); e[5] = f2bf(f1.y); e[6] = f2bf(f1.z); e[7] = f2bf(f1.w);
        } else {
            short8 s = *(const short8*)((const short*)src + idx);
            #pragma unroll
            for (int j = 0; j < 8; ++j) e[j] = s[j];
        }
        #pragma unroll
        for (int j = 0; j < 8; ++j) T[colg + j][row] = e[j];
    }
    __syncthreads();
    #pragma unroll
    for (int h = 0; h < 2; ++h) {
        const int orow = (tid >> 3) + 32 * h;
        const int ocolg = (tid & 7) * 8;
        const size_t idx = (size_t)(bC * 64 + orow) * (size_t)R + (size_t)(bR * 64 + ocolg);
        *(short8*)(dst + idx) = *(const short8*)&T[orow][ocolg];
    }
}

// ---------------- 64x64-tile GEMM v2: BK=64, dbuf, global_load_lds, XOR-swizzle ------
// C = (A@Bt^T + bias) * os. Two independent jobs selectable via blockIdx.z.
struct GJ { const short* A; const short* B; const void* bias; void* C; float os; };

template<int OSRC>
__global__ __launch_bounds__(256)
void gemm64_bt_k(GJ j0, GJ j1, const int* __restrict__ dflag)
{
    __shared__ __align__(16) short As[2][64][64];
    __shared__ __align__(16) short Bs[2][64][64];

    const GJ j = blockIdx.z ? j1 : j0;
    const int rtf = *dflag;

    const int tid  = threadIdx.x;
    const int bN   = blockIdx.x, bM = blockIdx.y;
    const int lane = tid & 63, wave = tid >> 6;
    const int wm   = (wave >> 1) * 32;
    const int wn   = (wave & 1) * 32;
    const int quad = lane >> 4, r16 = lane & 15;

    floatx4 acc[2][2];
    #pragma unroll
    for (int i = 0; i < 2; ++i)
        #pragma unroll
        for (int jj = 0; jj < 2; ++jj)
            acc[i][jj] = (floatx4){0.f, 0.f, 0.f, 0.f};

    const int srow = wave * 8 + (lane >> 3);
    const int scg  = (lane & 7) ^ ((lane >> 3) & 7);
    const short* gA = j.A + (size_t)(bM * 64 + srow) * 1024 + scg * 8;
    const short* gB = j.B + (size_t)(bN * 64 + srow) * 1024 + scg * 8;

#define STAGE(buf, k0)                                                          \
    {                                                                           \
        _Pragma("unroll")                                                       \
        for (int jj = 0; jj < 2; ++jj) {                                        \
            GLOAD16(gA + (size_t)jj * 32 * 1024 + (k0),                         \
                    &As[buf][wave * 8 + jj * 32][0]);                           \
            GLOAD16(gB + (size_t)jj * 32 * 1024 + (k0),                         \
                    &Bs[buf][wave * 8 + jj * 32][0]);                           \
        }                                                                       \
    }

    STAGE(0, 0);
    __syncthreads();

    const int sr = r16 & 7;
    int buf = 0;
    for (int t = 0; t < 16; ++t) {
        if (t < 15) STAGE(buf ^ 1, (t + 1) * 64);
        #pragma unroll
        for (int kk = 0; kk < 2; ++kk) {
            const int pc = ((kk * 4 + quad) ^ sr) * 8;
            const short8 a0 = *(const short8*)&As[buf][wm + r16][pc];
            const short8 a1 = *(const short8*)&As[buf][wm + 16 + r16][pc];
            const short8 b0 = *(const short8*)&Bs[buf][wn + r16][pc];
            const short8 b1 = *(const short8*)&Bs[buf][wn + 16 + r16][pc];
            acc[0][0] = __builtin_amdgcn_mfma_f32_16x16x32_bf16(a0, b0, acc[0][0], 0, 0, 0);
            acc[0][1] = __builtin_amdgcn_mfma_f32_16x16x32_bf16(a0, b1, acc[0][1], 0, 0, 0);
            acc[1][0] = __builtin_amdgcn_mfma_f32_16x16x32_bf16(a1, b0, acc[1][0], 0, 0, 0);
            acc[1][1] = __builtin_amdgcn_mfma_f32_16x16x32_bf16(a1, b1, acc[1][1], 0, 0, 0);
        }
        __syncthreads();
        buf ^= 1;
    }
#undef STAGE

    const bool of32 = (OSRC == SRC_F32) || (OSRC == SRC_RT && rtf);
    #pragma unroll
    for (int jj = 0; jj < 2; ++jj) {
        const int gc = bN * 64 + wn + jj * 16 + r16;
        const float bb = rtf ? ((const float*)j.bias)[gc]
                             : bf2f(((const unsigned short*)j.bias)[gc]);
        #pragma unroll
        for (int i = 0; i < 2; ++i) {
            #pragma unroll
            for (int rg = 0; rg < 4; ++rg) {
                const int gr = bM * 64 + wm + i * 16 + quad * 4 + rg;
                const float v = (acc[i][jj][rg] + bb) * j.os;
                if (of32)
                    ((float*)j.C)[(size_t)gr * 1024 + gc] = v;
                else
                    ((__hip_bfloat16*)j.C)[(size_t)gr * 1024 + gc] = __float2bfloat16(v);
            }
        }
    }
}

// ---------------- fused attention v8: swapped-operand main loop ----------------------
// Block = 16 Q-rows x 1 head, 256 threads (4 waves), LDS ~16.6 KB -> 8 blocks/CU.
// Wave w owns kcols [w*512, (w+1)*512), 8 steps x 64 kcols (4 tiles). S^T via
// mfma(A=K, B=Q): lane holds S[kc=tile+quad*4+reg][qrow=r16] -- all values for the
// lane's own row. Per step: 8 MFMA -> lane-local top-2 (16 merges) + 2 cross-quad
// shuffle stages -> 16-parallel atomicMax rmax -> per-lane append into private
// segment (wid = wave*4+quad, NSEG=12) with thr = max(g1-1,(g1+m2-1)/2) <= tau.
// Tail identical to R16: quad q of wave w owns row 4w+q; Michelot tau0 = g1-1;
// quad-ballot compact; uint2 PV, 4 out cols/lane.
__global__ __launch_bounds__(256, 8)
void attn_fused_k(const short* __restrict__ Qb, const short* __restrict__ Kb,
                  const short* __restrict__ Vb, short* __restrict__ Ob)
{
    __shared__ unsigned cpk[16][CAPP];
    __shared__ unsigned rmax[16];
    __shared__ int cnt[16];

    const int tid  = threadIdx.x;
    const int lane = tid & 63, wave = tid >> 6;
    const int quad = lane >> 4, r16 = lane & 15;

    // head->XCD pinning: blocks with bid%8==x carry heads x and x+8.
    const int bid  = blockIdx.x;
    const int slot = bid >> 3;
    const int h    = (slot & 1) * 8 + (bid & 7);
    const int row0 = (slot >> 1) * 16;

    if (tid < 16) { rmax[tid] = fmap(-3.0e38f); cnt[tid] = 0; }
    __syncthreads();

    // Q fragment (B-operand): col = qrow = row0 + r16, k-offset quad*8 (+32)
    const short* qp = Qb + (size_t)(row0 + r16) * 1024 + h * 64 + quad * 8;
    const short8 qb0 = *(const short8*)qp;
    const short8 qb1 = *(const short8*)(qp + 32);

    const int wid   = wave * 4 + quad;         // writer id 0..15 (per row)
    const int kbase = wave * 512;
    const short* kpA = Kb + (size_t)(kbase + r16) * 1024 + h * 64 + quad * 8;

    float rm1 = -3.0e38f, rm2 = -3.0e38f;
    int mycnt = 0;

    for (int s = 0; s < 8; ++s) {   // 8 steps x 64 kcols
        floatx4 acc[4];
        #pragma unroll
        for (int t = 0; t < 4; ++t) {
            const short* kp = kpA + (size_t)(s * 64 + t * 16) * 1024;
            const short8 a0 = *(const short8*)kp;
            const short8 a1 = *(const short8*)(kp + 32);
            floatx4 a = (floatx4){0.f, 0.f, 0.f, 0.f};
            a = __builtin_amdgcn_mfma_f32_16x16x32_bf16(a0, qb0, a, 0, 0, 0);
            a = __builtin_amdgcn_mfma_f32_16x16x32_bf16(a1, qb1, a, 0, 0, 0);
            acc[t] = a;   // scale 1/8 pre-folded into Qb
        }

        // lane-local top-2 over 16 values (all belong to row r16)
        float m1 = acc[0][0], m2 = -3.0e38f;
        #pragma unroll
        for (int t = 0; t < 4; ++t) {
            #pragma unroll
            for (int rg = 0; rg < 4; ++rg) {
                if (t == 0 && rg == 0) continue;
                const float v = acc[t][rg];
                m2 = fmaxf(m2, fminf(m1, v));
                m1 = fmaxf(m1, v);
            }
        }
        // cross-quad top-2 butterfly (same r16 = same row), offsets 16, 32
        #pragma unroll
        for (int off = 16; off < 64; off <<= 1) {
            const float o1 = __shfl_xor(m1, off, 64);
            const float o2 = __shfl_xor(m2, off, 64);
            const float n2 = fmaxf(fminf(m1, o1), (m1 >= o1) ? m2 : o2);
            m1 = fmaxf(m1, o1);
            m2 = n2;
        }
        // merge into running top-2; post m1 (16-parallel, distinct banks)
        rm2 = fmaxf(fminf(rm1, m1), (rm1 >= m1) ? rm2 : m2);
        rm1 = fmaxf(rm1, m1);
        if (quad == 0) atomicMax(&rmax[r16], fmap(m1));

        // per-lane append: thr = max(g1-1, (g1+m2-1)/2) <= tau (superset of support)
        const float g1 = fmaxf(funmap(rmax[r16]), rm1);
        const float thr = fmaxf(g1 - 1.0f, 0.5f * (g1 + rm2) - 0.5f);
        #pragma unroll
        for (int t = 0; t < 4; ++t) {
            #pragma unroll
            for (int rg = 0; rg < 4; ++rg) {
                const float val = acc[t][rg];
                if (val >= thr) {
                    const unsigned pk = ((unsigned)f2bfu(val) << 16)
                        | (unsigned)(kbase + s * 64 + t * 16 + quad * 4 + rg);
                    const int c = mycnt;
                    if (c < NSEG) {
                        cpk[r16][wid * NSEG + c] = pk;
                    } else {
                        const int p = atomicAdd(&cnt[r16], 1);
                        if (p < OVF) cpk[r16][OVBASE + p] = pk;
                    }
                    mycnt = c + 1;
                }
            }
        }
    }

    // sentinel-fill unused private slots (bf16 -inf packed)
    for (int k = mycnt; k < NSEG; ++k)
        cpk[r16][wid * NSEG + k] = 0xFF800000u;
    __syncthreads();   // all appends + final rmax visible

    // ---- row-parallel tail: quad q of wave w owns row 4w+q (identical to R16) ----
    const int r = wave * 4 + quad;
    const int novf = min(cnt[r], OVF);

    // 16 candidates per lane; k>=12 are overflow slots, guarded by novf
    unsigned ca[16];
    #pragma unroll
    for (int k = 0; k < 12; ++k) ca[k] = cpk[r][k * 16 + r16];
    #pragma unroll
    for (int k = 12; k < 16; ++k) {
        const int oi = k * 16 + r16 - OVBASE;
        ca[k] = (oi < novf) ? cpk[r][k * 16 + r16] : 0xFF800000u;
    }

    // Michelot from exact tau0 = g1-1 (monotone increasing; sentinels never activate)
    float tau = funmap(rmax[r]) - 1.0f;
    float prevc = -1.0f;
    for (int it = 0; it < 18; ++it) {
        float s = 0.f, c = 0.f;
        #pragma unroll
        for (int k = 0; k < 16; ++k) {
            const float v = __uint_as_float(ca[k] & 0xFFFF0000u);
            if (v > tau) { s += v; c += 1.f; }
        }
        #pragma unroll
        for (int off = 1; off < 16; off <<= 1) {
            s += __shfl_xor(s, off, 64);
            c += __shfl_xor(c, off, 64);
        }
        if (c == prevc || c == 0.f) break;
        prevc = c;
        tau = (s - 1.0f) / c;
    }

    // quad-ballot compact of support (p>0) to list front, p packed bf16
    const unsigned qpre = (1u << r16) - 1u;
    int base = 0;
    #pragma unroll
    for (int k = 0; k < 16; ++k) {
        const float v = __uint_as_float(ca[k] & 0xFFFF0000u);
        const float p = v - tau;
        const bool keep = (p > 0.f);
        const unsigned long long mm = __ballot(keep);
        const unsigned qm = (unsigned)((mm >> (quad * 16)) & 0xFFFFull);
        if (keep)
            cpk[r][base + __popc(qm & qpre)] =
                ((unsigned)f2bfu(p) << 16) | (ca[k] & 0xFFFFu);
        base += __popc(qm);
    }
    const int msup = base;

    // PV gather: lane covers out cols r16*4..+3 (uint2); rows parallel across quads
    const unsigned short* vb = (const unsigned short*)Vb + (size_t)h * 64 + r16 * 4;
    float o0 = 0.f, o1 = 0.f, o2 = 0.f, o3 = 0.f;
    int jj = 0;
    for (; jj + 2 <= msup; jj += 2) {
        const unsigned ua = cpk[r][jj], ub = cpk[r][jj + 1];
        const float pa = __uint_as_float(ua & 0xFFFF0000u);
        const float pb = __uint_as_float(ub & 0xFFFF0000u);
        const uint2 da = *(const uint2*)(vb + (size_t)(ua & 0xFFFFu) * 1024);
        const uint2 db = *(const uint2*)(vb + (size_t)(ub & 0xFFFFu) * 1024);
        o0 += pa * __uint_as_float(da.x << 16);
        o1 += pa * __uint_as_float(da.x & 0xFFFF0000u);
        o2 += pa * __uint_as_float(da.y << 16);
        o3 += pa * __uint_as_float(da.y & 0xFFFF0000u);
        o0 += pb * __uint_as_float(db.x << 16);
        o1 += pb * __uint_as_float(db.x & 0xFFFF0000u);
        o2 += pb * __uint_as_float(db.y << 16);
        o3 += pb * __uint_as_float(db.y & 0xFFFF0000u);
    }
    if (jj < msup) {
        const unsigned ua = cpk[r][jj];
        const float pa = __uint_as_float(ua & 0xFFFF0000u);
        const uint2 da = *(const uint2*)(vb + (size_t)(ua & 0xFFFFu) * 1024);
        o0 += pa * __uint_as_float(da.x << 16);
        o1 += pa * __uint_as_float(da.x & 0xFFFF0000u);
        o2 += pa * __uint_as_float(da.y << 16);
        o3 += pa * __uint_as_float(da.y & 0xFFFF0000u);
    }

    short* op = Ob + ((size_t)h * 2048 + row0 + r) * 64 + r16 * 4;
    op[0] = f2bf(o0); op[1] = f2bf(o1); op[2] = f2bf(o2); op[3] = f2bf(o3);
}

extern "C" void kernel_launch(void* const* d_in, const int* in_sizes, int n_in,
                              void* d_out, int out_size, void* d_ws, size_t ws_size,
                              hipStream_t stream)
{
    (void)in_sizes; (void)n_in; (void)out_size; (void)ws_size;

    const void* queries = d_in[0];
    const void* keys    = d_in[1];
    // d_in[2] ("values") unused by the reference.
    const void* Wq = d_in[3];
    const void* bq = d_in[4];
    const void* Wk = d_in[5];
    const void* bk = d_in[6];
    const void* Wv = d_in[7];
    const void* bv = d_in[8];
    const void* Wo = d_in[9];
    const void* bo = d_in[10];

    const int L = 2048, DM = 1024;
    const size_t LD = (size_t)L * DM;   // 2M elements

    int*   flag = (int*)d_ws;
    short* Qc  = (short*)((char*)d_ws + 256);  // bf16 queries      [2048,1024]
    short* Kc  = Qc + LD;                      // bf16 keys         [2048,1024]
    short* WqT = Kc + LD;                      // bf16 Wq^T         [1024,1024]
    short* WkT = WqT + (size_t)DM * DM;
    short* WvT = WkT + (size_t)DM * DM;
    short* WoT = WvT + (size_t)DM * DM;
    short* Qb  = WoT + (size_t)DM * DM;        // [2048,1024] (pre-scaled by 1/8)
    short* Kb  = Qb + LD;
    short* Vb  = Kb + LD;
    short* Ob  = Vb + LD;                      // [H,2048,64] contiguous (== mixed view)

    dim3 blk(256);

    // 0) dtype detection
    detect_k<<<dim3(1), dim3(64), 0, stream>>>((const short*)queries, 4096, flag);

    // p1) convert queries/keys -> bf16
    convert2_k<<<dim3((unsigned)(LD / 2048), 1, 2), blk, 0, stream>>>(
        queries, keys, Qc, Kc, flag);

    // p2) transpose-convert the 4 weight matrices -> bf16 [N][K]
    {
        TP4 p;
        p.s[0] = Wq; p.s[1] = Wk; p.s[2] = Wv; p.s[3] = Wo;
        p.d[0] = WqT; p.d[1] = WkT; p.d[2] = WvT; p.d[3] = WoT;
        transpose4_k<<<dim3(DM / 64, DM / 64, 4), blk, 0, stream>>>(p, DM, DM, flag);
    }

    // 1) Qb & Kb projections batched (Q job pre-scales by 1/8; exact pow2)
    {
        GJ jq{(const short*)Qc, WqT, bq, Qb, 0.125f};
        GJ jk{(const short*)Kc, WkT, bk, Kb, 1.0f};
        gemm64_bt_k<SRC_BF16><<<dim3(DM / 64, L / 64, 2), blk, 0, stream>>>(jq, jk, flag);
    }
    // 2) Vb = Kb @ WvT + bv   (reference quirk: V from key projection)
    {
        GJ jv{(const short*)Kb, WvT, bv, Vb, 1.0f};
        gemm64_bt_k<SRC_BF16><<<dim3(DM / 64, L / 64, 1), blk, 0, stream>>>(jv, jv, flag);
    }

    // 3) fused attention (scores never reach HBM; barrier-free main loop)
    attn_fused_k<<<dim3((L / 16) * 16), blk, 0, stream>>>(Qb, Kb, Vb, Ob);

    // 4) out = Ob(viewed [2048,1024]) @ WoT + bo -> d_out (dtype per flag)
    {
        GJ jo{(const short*)Ob, WoT, bo, d_out, 1.0f};
        gemm64_bt_k<SRC_RT><<<dim3(DM / 64, L / 64, 1), blk, 0, stream>>>(jo, jo, flag);
    }
}